// Round 1
// baseline (554.415 us; speedup 1.0000x reference)
//
#include <hip/hip_runtime.h>

typedef _Float16 f16;
typedef f16 f16x8 __attribute__((ext_vector_type(8)));
typedef float f32x4 __attribute__((ext_vector_type(4)));

#define AS1 __attribute__((address_space(1)))
#define AS3 __attribute__((address_space(3)))

#define NN 8192
#define EE 32768

__device__ __forceinline__ void glds16(const void* g, void* l) {
  __builtin_amdgcn_global_load_lds((const AS1 unsigned int*)g, (AS3 unsigned int*)l, 16, 0, 0);
}
// cooperative stage, 256 threads, 16B/lane; LDS base passed wave-uniform
__device__ __forceinline__ void stage_bytes(const void* g, void* s, int nbytes, int tid) {
  const int lane = tid & 63;
  for (int off = tid * 16; off < nbytes; off += 4096)
    glds16((const char*)g + off, (char*)s + (off - lane * 16));
}

// ---------------- prep: h0 GEMM, edge-hidden, W2 repack, weight casts ----------------
__global__ void prep_kernel(
    const float* __restrict__ nf, const float* __restrict__ ef,
    const float* __restrict__ W_in, const float* __restrict__ b_in,
    const float* __restrict__ W1, const float* __restrict__ b1,
    const float* __restrict__ W2, const float* __restrict__ b2,
    const float* __restrict__ gWih, const float* __restrict__ gWhh,
    const float* __restrict__ lWih, const float* __restrict__ lWhh,
    float* __restrict__ h, f16* __restrict__ hf, f16* __restrict__ ehh,
    f16* __restrict__ W2rt, f16* __restrict__ WihT, f16* __restrict__ WhhT,
    f16* __restrict__ Wli, f16* __restrict__ Wlh) {
  int t = blockIdx.x * 256 + threadIdx.x;
  if (t < 786432) {                       // h0: [8192][96] fp32+f16, pads zero
    int n = t / 96, i = t - n * 96;
    float v = 0.f;
    if (i < 73) {
      v = b_in[i];
      const float* nr = nf + n * 32;
      #pragma unroll
      for (int f = 0; f < 32; ++f) v += nr[f] * W_in[f * 73 + i];
    }
    h[t] = v; hf[t] = (f16)v;
    return;
  }
  t -= 786432;
  if (t < 2621440) {                      // ehh: [32768][80], col73 = 1.0 (bias slot)
    int e = t / 80, k = t - e * 80;
    float v;
    if (k < 73) {
      v = b1[k];
      const float* er = ef + e * 16;
      #pragma unroll
      for (int f = 0; f < 16; ++f) v += er[f] * W1[f * 73 + k];
      v = fmaxf(v, 0.f);
    } else v = (k == 73) ? 1.f : 0.f;
    ehh[t] = (f16)v;
    return;
  }
  t -= 2621440;
  if (t < 568320) {                       // W2rt: [74 kg][80 i][96 j]; kg=73 holds b2
    int kg = t / 7680, r = t - kg * 7680;
    int i = r / 96, j = r - i * 96;
    float v = 0.f;
    if (i < 73 && j < 73) v = (kg < 73) ? W2[kg * 5329 + i * 73 + j] : b2[i * 73 + j];
    W2rt[t] = (f16)v;
    return;
  }
  t -= 568320;
  if (t < 43008) {                        // WihT/WhhT: [224][96]
    int half = t / 21504, r = t - half * 21504;
    int g = r / 96, k = r - g * 96;
    float v = 0.f;
    if (g < 219 && k < 73) v = half ? gWhh[g * 73 + k] : gWih[g * 73 + k];
    (half ? WhhT : WihT)[r] = (f16)v;
    return;
  }
  t -= 43008;
  if (t < 44384) {                        // Wli: [292][152]
    int g = t / 152, k = t - g * 152;
    Wli[t] = (f16)((k < 146) ? lWih[g * 146 + k] : 0.f);
    return;
  }
  t -= 44384;
  if (t < 23360) {                        // Wlh: [292][80]
    int g = t / 80, k = t - g * 80;
    Wlh[t] = (f16)((k < 73) ? lWhh[g * 73 + k] : 0.f);
  }
}

// ---------------- fused edge-network matvec + scatter ----------------
// agg[tgt[e], i] += sum_{kg,j} ehh[e,kg] * hs[e,j] * W2rt[kg][i][j]
// M=32768(e), N=80(i), K = 74*96 (kg-major, j inner). A-frag generated in regs.
__global__ __launch_bounds__(256, 1) void vgemm_kernel(
    const f16* __restrict__ ehh, const float* __restrict__ h,
    const f16* __restrict__ W2rt, const int* __restrict__ Esrc,
    const int* __restrict__ Etgt, float* __restrict__ agg) {
  __shared__ __align__(16) f16 ehs[256 * 80];
  __shared__ __align__(16) f16 w2s[2][80 * 96];
  const int tid = threadIdx.x;
  const int bm = blockIdx.x & 127;
  const int ksplit = blockIdx.x >> 7;
  const int e0 = bm * 256;
  const int wave = tid >> 6, lane = tid & 63;
  const int q = lane >> 4, mr = lane & 15;
  const int kg0 = ksplit * 37;

  stage_bytes(ehh + e0 * 80, ehs, 256 * 80 * 2, tid);

  // hs fragments in registers: wave owns 4 m-tiles (rows e0+wave*64+mt*16+mr)
  f16x8 hsv[4][3];
  int srcn[4];
  #pragma unroll
  for (int mt = 0; mt < 4; ++mt) srcn[mt] = Esrc[e0 + wave * 64 + mt * 16 + mr];
  #pragma unroll
  for (int mt = 0; mt < 4; ++mt) {
    #pragma unroll
    for (int ks = 0; ks < 3; ++ks) {
      const float* hp = h + srcn[mt] * 96 + ks * 32 + q * 8;
      float4 a = *(const float4*)hp;
      float4 bb = *(const float4*)(hp + 4);
      f16x8 v;
      v[0] = (f16)a.x; v[1] = (f16)a.y; v[2] = (f16)a.z; v[3] = (f16)a.w;
      v[4] = (f16)bb.x; v[5] = (f16)bb.y; v[6] = (f16)bb.z; v[7] = (f16)bb.w;
      hsv[mt][ks] = v;
    }
  }

  stage_bytes(W2rt + kg0 * 7680, w2s[0], 15360, tid);

  f32x4 zero = {0.f, 0.f, 0.f, 0.f};
  f32x4 acc[4][5];
  #pragma unroll
  for (int mt = 0; mt < 4; ++mt)
    #pragma unroll
    for (int nt = 0; nt < 5; ++nt) acc[mt][nt] = zero;

  #pragma unroll 2
  for (int it = 0; it < 37; ++it) {
    __syncthreads();
    if (it + 1 < 37) stage_bytes(W2rt + (kg0 + it + 1) * 7680, w2s[(it + 1) & 1], 15360, tid);
    const int kg = kg0 + it;
    f16x8 af[4][3];
    #pragma unroll
    for (int mt = 0; mt < 4; ++mt) {
      f16 ev = ehs[(wave * 64 + mt * 16 + mr) * 80 + kg];
      f16x8 evv = {ev, ev, ev, ev, ev, ev, ev, ev};
      #pragma unroll
      for (int ks = 0; ks < 3; ++ks) af[mt][ks] = hsv[mt][ks] * evv;
    }
    const f16* wb = w2s[it & 1];
    #pragma unroll
    for (int nt = 0; nt < 5; ++nt) {
      #pragma unroll
      for (int ks = 0; ks < 3; ++ks) {
        f16x8 bf = *(const f16x8*)(wb + (nt * 16 + mr) * 96 + ks * 32 + q * 8);
        #pragma unroll
        for (int mt = 0; mt < 4; ++mt)
          acc[mt][nt] = __builtin_amdgcn_mfma_f32_16x16x32_f16(af[mt][ks], bf, acc[mt][nt], 0, 0, 0);
      }
    }
  }
  // epilogue: C layout col=lane&15, row=(lane>>4)*4+reg; scatter to targets
  #pragma unroll
  for (int mt = 0; mt < 4; ++mt) {
    #pragma unroll
    for (int reg = 0; reg < 4; ++reg) {
      int er = e0 + wave * 64 + mt * 16 + q * 4 + reg;
      int tg = Etgt[er];
      float* ap = agg + tg * 80;
      #pragma unroll
      for (int nt = 0; nt < 5; ++nt) {
        int i = nt * 16 + mr;
        if (i < 73) atomicAdd(ap + i, acc[mt][nt][reg]);
      }
    }
  }
}

// ---------------- agg fp32 -> f16 (padded) ----------------
__global__ void castagg_kernel(const float* __restrict__ agg, f16* __restrict__ aggf) {
  int t = blockIdx.x * 256 + threadIdx.x;  // exactly 786432
  int n = t / 96, k = t - n * 96;
  aggf[t] = (f16)((k < 73) ? agg[n * 80 + k] : 0.f);
}

// ---------------- GRU gates GEMMs: G[0]=agg@WihT, G[1]=h@WhhT ----------------
__global__ __launch_bounds__(256, 1) void grugemm_kernel(
    const f16* __restrict__ aggf, const f16* __restrict__ hf,
    const f16* __restrict__ WihT, const f16* __restrict__ WhhT,
    float* __restrict__ G) {
  __shared__ __align__(16) f16 As[128 * 96];
  __shared__ __align__(16) f16 Bs[224 * 96];
  const int tid = threadIdx.x;
  const int bz = blockIdx.x >> 6, bm = blockIdx.x & 63;
  const int m0 = bm * 128;
  const f16* A = bz ? hf : aggf;
  const f16* B = bz ? WhhT : WihT;
  float* out = G + bz * (NN * 224);
  stage_bytes(A + m0 * 96, As, 128 * 96 * 2, tid);
  stage_bytes(B, Bs, 224 * 96 * 2, tid);
  const int wave = tid >> 6, lane = tid & 63, q = lane >> 4, mr = lane & 15;
  __syncthreads();
  f16x8 af[2][3];
  #pragma unroll
  for (int mt = 0; mt < 2; ++mt)
    #pragma unroll
    for (int ks = 0; ks < 3; ++ks)
      af[mt][ks] = *(const f16x8*)(As + (wave * 32 + mt * 16 + mr) * 96 + ks * 32 + q * 8);
  f32x4 zero = {0.f, 0.f, 0.f, 0.f};
  f32x4 acc[2][14];
  #pragma unroll
  for (int mt = 0; mt < 2; ++mt)
    #pragma unroll
    for (int nt = 0; nt < 14; ++nt) acc[mt][nt] = zero;
  #pragma unroll
  for (int nt = 0; nt < 14; ++nt) {
    #pragma unroll
    for (int ks = 0; ks < 3; ++ks) {
      f16x8 bf = *(const f16x8*)(Bs + (nt * 16 + mr) * 96 + ks * 32 + q * 8);
      #pragma unroll
      for (int mt = 0; mt < 2; ++mt)
        acc[mt][nt] = __builtin_amdgcn_mfma_f32_16x16x32_f16(af[mt][ks], bf, acc[mt][nt], 0, 0, 0);
    }
  }
  #pragma unroll
  for (int mt = 0; mt < 2; ++mt)
    #pragma unroll
    for (int reg = 0; reg < 4; ++reg) {
      int row = m0 + wave * 32 + mt * 16 + q * 4 + reg;
      #pragma unroll
      for (int nt = 0; nt < 14; ++nt)
        out[row * 224 + nt * 16 + mr] = acc[mt][nt][reg];
    }
}

// ---------------- GRU elementwise update ----------------
__global__ void gate_kernel(const float* __restrict__ G, const float* __restrict__ bih,
                            const float* __restrict__ bhh, float* __restrict__ h,
                            f16* __restrict__ hf) {
  int idx = blockIdx.x * 256 + threadIdx.x;  // exactly 8192*73
  int n = idx / 73, i = idx - n * 73;
  const float* g0 = G + n * 224;
  const float* g1 = G + NN * 224 + n * 224;
  float rr = g0[i] + bih[i] + g1[i] + bhh[i];
  rr = 1.f / (1.f + expf(-rr));
  float zz = g0[73 + i] + bih[73 + i] + g1[73 + i] + bhh[73 + i];
  zz = 1.f / (1.f + expf(-zz));
  float nn_ = tanhf(g0[146 + i] + bih[146 + i] + rr * (g1[146 + i] + bhh[146 + i]));
  float hv = h[n * 96 + i];
  float hn = (1.f - zz) * nn_ + zz * hv;
  h[n * 96 + i] = hn;
  hf[n * 96 + i] = (f16)hn;
}

// ---------------- Set2Set: one block per batch segment, 12 internal iterations ----------------
__global__ __launch_bounds__(384, 1) void s2s_kernel(
    const float* __restrict__ h, const f16* __restrict__ Wli, const f16* __restrict__ Wlh,
    const float* __restrict__ lbih, const float* __restrict__ lbhh,
    const float* __restrict__ Wout, const float* __restrict__ bout,
    const int* __restrict__ batch, float* __restrict__ out) {
  __shared__ float qstar[152];
  __shared__ float hhv[80];
  __shared__ float ccv[73];
  __shared__ float gates[292];
  __shared__ float earr[1024];
  __shared__ float red[512];
  __shared__ float rpart[5 * 73];
  __shared__ int sseg[2];
  const int t = threadIdx.x, b = blockIdx.x;
  if (t < 2) {
    int key = b + t, lo = 0, hi = NN;
    while (lo < hi) { int mid = (lo + hi) >> 1; if (batch[mid] < key) lo = mid + 1; else hi = mid; }
    sseg[t] = lo;
  }
  if (t < 152) qstar[t] = 0.f;
  if (t < 80) hhv[t] = 0.f;
  if (t < 73) ccv[t] = 0.f;
  f16x8 wih_r[19], whh_r[10];
  float bsum = 0.f;
  if (t < 292) {
    bsum = lbih[t] + lbhh[t];
    #pragma unroll
    for (int v = 0; v < 19; ++v) wih_r[v] = *(const f16x8*)(Wli + t * 152 + v * 8);
    #pragma unroll
    for (int v = 0; v < 10; ++v) whh_r[v] = *(const f16x8*)(Wlh + t * 80 + v * 8);
  }
  __syncthreads();
  const int s0 = sseg[0];
  int seg = sseg[1] - s0;
  if (seg > 1024) seg = 1024;
  const int s1 = s0 + seg;
  for (int iter = 0; iter < 12; ++iter) {
    if (t < 292) {
      float acc = bsum;
      #pragma unroll
      for (int v = 0; v < 19; ++v) {
        f16x8 w = wih_r[v];
        #pragma unroll
        for (int el = 0; el < 8; ++el) acc += (float)w[el] * qstar[v * 8 + el];
      }
      #pragma unroll
      for (int v = 0; v < 10; ++v) {
        f16x8 w = whh_r[v];
        #pragma unroll
        for (int el = 0; el < 8; ++el) acc += (float)w[el] * hhv[v * 8 + el];
      }
      gates[t] = acc;
    }
    __syncthreads();
    if (t < 73) {
      float ig = 1.f / (1.f + expf(-gates[t]));
      float fg = 1.f / (1.f + expf(-gates[73 + t]));
      float gg = tanhf(gates[146 + t]);
      float og = 1.f / (1.f + expf(-gates[219 + t]));
      float c = fg * ccv[t] + ig * gg;
      ccv[t] = c;
      hhv[t] = og * tanhf(c);
    }
    __syncthreads();
    // attention logits
    float lmax = -3.4e38f;
    for (int n = s0 + t; n < s1; n += 384) {
      const float* hr = h + n * 96;
      float e = 0.f;
      for (int i = 0; i < 72; i += 4) {
        float4 hv = *(const float4*)(hr + i);
        e += hv.x * hhv[i] + hv.y * hhv[i + 1] + hv.z * hhv[i + 2] + hv.w * hhv[i + 3];
      }
      e += hr[72] * hhv[72];
      earr[n - s0] = e;
      lmax = fmaxf(lmax, e);
    }
    red[t] = lmax;
    if (t < 128) red[384 + t] = -3.4e38f;
    __syncthreads();
    for (int sft = 256; sft > 0; sft >>= 1) {
      if (t < sft) red[t] = fmaxf(red[t], red[t + sft]);
      __syncthreads();
    }
    float mx = red[0];
    __syncthreads();
    float lsum = 0.f;
    for (int ii = t; ii < seg; ii += 384) {
      float a = expf(earr[ii] - mx);
      earr[ii] = a;
      lsum += a;
    }
    red[t] = lsum;
    if (t < 128) red[384 + t] = 0.f;
    __syncthreads();
    for (int sft = 256; sft > 0; sft >>= 1) {
      if (t < sft) red[t] += red[t + sft];
      __syncthreads();
    }
    float S = red[0];
    // weighted readout r
    if (t < 365) {
      int ch = t / 73, i = t - ch * 73;
      float r = 0.f;
      for (int ii = ch; ii < seg; ii += 5) r += earr[ii] * h[(s0 + ii) * 96 + i];
      rpart[ch * 73 + i] = r;
    }
    __syncthreads();
    if (t < 73) {
      float r = rpart[t] + rpart[73 + t] + rpart[146 + t] + rpart[219 + t] + rpart[292 + t];
      float invS = (S > 0.f) ? (1.f / S) : 0.f;
      qstar[t] = hhv[t];
      qstar[73 + t] = r * invS;
    }
    __syncthreads();
  }
  if (t == 0) {
    float a = bout[0];
    for (int i = 0; i < 73; ++i) a += hhv[i] * Wout[i];
    out[b] = a;
  }
}

// ---------------- workspace layout (bytes) ----------------
#define OFF_H      0u          // float [8192][96]
#define OFF_AGG    3145728u    // float [8192][80]
#define OFF_G      5767168u    // float [2][8192][224]
#define OFF_HF     20447232u   // f16 [8192][96]
#define OFF_AGGF   22020096u   // f16 [8192][96]
#define OFF_EHH    23592960u   // f16 [32768][80]
#define OFF_W2RT   28835840u   // f16 [74][80][96]
#define OFF_WIHT   29972480u   // f16 [224][96]
#define OFF_WHHT   30015488u   // f16 [224][96]
#define OFF_WLI    30058496u   // f16 [292][152]
#define OFF_WLH    30147264u   // f16 [292][80]

extern "C" void kernel_launch(void* const* d_in, const int* in_sizes, int n_in,
                              void* d_out, int out_size, void* d_ws, size_t ws_size,
                              hipStream_t stream) {
  const float* nf   = (const float*)d_in[0];
  const float* ef   = (const float*)d_in[1];
  const float* W_in = (const float*)d_in[2];
  const float* b_in = (const float*)d_in[3];
  const float* W1   = (const float*)d_in[4];
  const float* b1   = (const float*)d_in[5];
  const float* W2   = (const float*)d_in[6];
  const float* b2   = (const float*)d_in[7];
  const float* gWih = (const float*)d_in[8];
  const float* gWhh = (const float*)d_in[9];
  const float* gbih = (const float*)d_in[10];
  const float* gbhh = (const float*)d_in[11];
  const float* lWih = (const float*)d_in[12];
  const float* lWhh = (const float*)d_in[13];
  const float* lbih = (const float*)d_in[14];
  const float* lbhh = (const float*)d_in[15];
  const float* Wout = (const float*)d_in[16];
  const float* bout = (const float*)d_in[17];
  const int* Esrc   = (const int*)d_in[18];
  const int* Etgt   = (const int*)d_in[19];
  const int* batch  = (const int*)d_in[20];

  char* ws = (char*)d_ws;
  float* h    = (float*)(ws + OFF_H);
  float* agg  = (float*)(ws + OFF_AGG);
  float* G    = (float*)(ws + OFF_G);
  f16* hf     = (f16*)(ws + OFF_HF);
  f16* aggf   = (f16*)(ws + OFF_AGGF);
  f16* ehh    = (f16*)(ws + OFF_EHH);
  f16* W2rt   = (f16*)(ws + OFF_W2RT);
  f16* WihT   = (f16*)(ws + OFF_WIHT);
  f16* WhhT   = (f16*)(ws + OFF_WHHT);
  f16* Wli    = (f16*)(ws + OFF_WLI);
  f16* Wlh    = (f16*)(ws + OFF_WLH);

  prep_kernel<<<15965, 256, 0, stream>>>(nf, ef, W_in, b_in, W1, b1, W2, b2,
                                         gWih, gWhh, lWih, lWhh,
                                         h, hf, ehh, W2rt, WihT, WhhT, Wli, Wlh);
  for (int step = 0; step < 3; ++step) {
    hipMemsetAsync(agg, 0, NN * 80 * sizeof(float), stream);
    vgemm_kernel<<<256, 256, 0, stream>>>(ehh, h, W2rt, Esrc, Etgt, agg);
    castagg_kernel<<<3072, 256, 0, stream>>>(agg, aggf);
    grugemm_kernel<<<128, 256, 0, stream>>>(aggf, hf, WihT, WhhT, G);
    gate_kernel<<<2336, 256, 0, stream>>>(G, gbih, gbhh, h, hf);
  }
  s2s_kernel<<<64, 384, 0, stream>>>(h, Wli, Wlh, lbih, lbhh, Wout, bout, batch,
                                     (float*)d_out);
}

// Round 2
// 445.242 us; speedup vs baseline: 1.2452x; 1.2452x over previous
//
#include <hip/hip_runtime.h>

typedef _Float16 f16;
typedef f16 f16x2 __attribute__((ext_vector_type(2)));
typedef f16 f16x8 __attribute__((ext_vector_type(8)));
typedef float f32x4 __attribute__((ext_vector_type(4)));

#define AS1 __attribute__((address_space(1)))
#define AS3 __attribute__((address_space(3)))

#define NN 8192
#define EE 32768

#if __has_builtin(__builtin_amdgcn_fdot2)
#define HAS_FDOT2 1
#else
#define HAS_FDOT2 0
#endif

__device__ __forceinline__ void glds16(const void* g, void* l) {
  __builtin_amdgcn_global_load_lds((const AS1 unsigned int*)g, (AS3 unsigned int*)l, 16, 0, 0);
}
// cooperative stage, 256 threads, 16B/lane; LDS base passed wave-uniform
__device__ __forceinline__ void stage_bytes(const void* g, void* s, int nbytes, int tid) {
  const int lane = tid & 63;
  for (int off = tid * 16; off < nbytes; off += 4096)
    glds16((const char*)g + off, (char*)s + (off - lane * 16));
}

// ---------------- prep: h0 GEMM, edge-hidden, W2 repack, weight casts ----------------
__global__ void prep_kernel(
    const float* __restrict__ nf, const float* __restrict__ ef,
    const float* __restrict__ W_in, const float* __restrict__ b_in,
    const float* __restrict__ W1, const float* __restrict__ b1,
    const float* __restrict__ W2, const float* __restrict__ b2,
    const float* __restrict__ gWih, const float* __restrict__ gWhh,
    const float* __restrict__ lWih, const float* __restrict__ lWhh,
    float* __restrict__ h, f16* __restrict__ hf, f16* __restrict__ ehh,
    f16* __restrict__ W2rt, f16* __restrict__ WihT, f16* __restrict__ WhhT,
    f16* __restrict__ Wli, f16* __restrict__ Wlh) {
  int t = blockIdx.x * 256 + threadIdx.x;
  if (t < 786432) {                       // h0: [8192][96] fp32+f16, pads zero
    int n = t / 96, i = t - n * 96;
    float v = 0.f;
    if (i < 73) {
      v = b_in[i];
      const float* nr = nf + n * 32;
      #pragma unroll
      for (int f = 0; f < 32; ++f) v += nr[f] * W_in[f * 73 + i];
    }
    h[t] = v; hf[t] = (f16)v;
    return;
  }
  t -= 786432;
  if (t < 2621440) {                      // ehh: [32768][80], col73 = 1.0 (bias slot)
    int e = t / 80, k = t - e * 80;
    float v;
    if (k < 73) {
      v = b1[k];
      const float* er = ef + e * 16;
      #pragma unroll
      for (int f = 0; f < 16; ++f) v += er[f] * W1[f * 73 + k];
      v = fmaxf(v, 0.f);
    } else v = (k == 73) ? 1.f : 0.f;
    ehh[t] = (f16)v;
    return;
  }
  t -= 2621440;
  if (t < 568320) {                       // W2rt: [74 kg][80 i][96 j]; kg=73 holds b2
    int kg = t / 7680, r = t - kg * 7680;
    int i = r / 96, j = r - i * 96;
    float v = 0.f;
    if (i < 73 && j < 73) v = (kg < 73) ? W2[kg * 5329 + i * 73 + j] : b2[i * 73 + j];
    W2rt[t] = (f16)v;
    return;
  }
  t -= 568320;
  if (t < 43008) {                        // WihT/WhhT: [224][96]
    int half = t / 21504, r = t - half * 21504;
    int g = r / 96, k = r - g * 96;
    float v = 0.f;
    if (g < 219 && k < 73) v = half ? gWhh[g * 73 + k] : gWih[g * 73 + k];
    (half ? WhhT : WihT)[r] = (f16)v;
    return;
  }
  t -= 43008;
  if (t < 44384) {                        // Wli: [292][152]
    int g = t / 152, k = t - g * 152;
    Wli[t] = (f16)((k < 146) ? lWih[g * 146 + k] : 0.f);
    return;
  }
  t -= 44384;
  if (t < 23360) {                        // Wlh: [292][80]
    int g = t / 80, k = t - g * 80;
    Wlh[t] = (f16)((k < 73) ? lWhh[g * 73 + k] : 0.f);
  }
}

// ---------------- fused edge-network matvec + scatter ----------------
// agg[tgt[e], i] += sum_{kg,j} ehh[e,kg] * hs[e,j] * W2rt[kg][i][j]
// M=32768(e), N=80(i), K = 74*96 (kg-major, j inner). A-frag generated in regs.
__global__ __launch_bounds__(256, 1) void vgemm_kernel(
    const f16* __restrict__ ehh, const float* __restrict__ h,
    const f16* __restrict__ W2rt, const int* __restrict__ Esrc,
    const int* __restrict__ Etgt, float* __restrict__ agg) {
  __shared__ __align__(16) f16 ehs[256 * 80];
  __shared__ __align__(16) f16 w2s[2][80 * 96];
  const int tid = threadIdx.x;
  const int bm = blockIdx.x & 127;
  const int ksplit = blockIdx.x >> 7;
  const int e0 = bm * 256;
  const int wave = tid >> 6, lane = tid & 63;
  const int q = lane >> 4, mr = lane & 15;
  const int kg0 = ksplit * 37;

  stage_bytes(ehh + e0 * 80, ehs, 256 * 80 * 2, tid);

  // hs fragments in registers: wave owns 4 m-tiles (rows e0+wave*64+mt*16+mr)
  f16x8 hsv[4][3];
  int srcn[4];
  #pragma unroll
  for (int mt = 0; mt < 4; ++mt) srcn[mt] = Esrc[e0 + wave * 64 + mt * 16 + mr];
  #pragma unroll
  for (int mt = 0; mt < 4; ++mt) {
    #pragma unroll
    for (int ks = 0; ks < 3; ++ks) {
      const float* hp = h + srcn[mt] * 96 + ks * 32 + q * 8;
      float4 a = *(const float4*)hp;
      float4 bb = *(const float4*)(hp + 4);
      f16x8 v;
      v[0] = (f16)a.x; v[1] = (f16)a.y; v[2] = (f16)a.z; v[3] = (f16)a.w;
      v[4] = (f16)bb.x; v[5] = (f16)bb.y; v[6] = (f16)bb.z; v[7] = (f16)bb.w;
      hsv[mt][ks] = v;
    }
  }

  stage_bytes(W2rt + kg0 * 7680, w2s[0], 15360, tid);

  f32x4 zero = {0.f, 0.f, 0.f, 0.f};
  f32x4 acc[4][5];
  #pragma unroll
  for (int mt = 0; mt < 4; ++mt)
    #pragma unroll
    for (int nt = 0; nt < 5; ++nt) acc[mt][nt] = zero;

  #pragma unroll 2
  for (int it = 0; it < 37; ++it) {
    __syncthreads();
    if (it + 1 < 37) stage_bytes(W2rt + (kg0 + it + 1) * 7680, w2s[(it + 1) & 1], 15360, tid);
    const int kg = kg0 + it;
    f16x8 af[4][3];
    #pragma unroll
    for (int mt = 0; mt < 4; ++mt) {
      f16 ev = ehs[(wave * 64 + mt * 16 + mr) * 80 + kg];
      f16x8 evv = {ev, ev, ev, ev, ev, ev, ev, ev};
      #pragma unroll
      for (int ks = 0; ks < 3; ++ks) af[mt][ks] = hsv[mt][ks] * evv;
    }
    const f16* wb = w2s[it & 1];
    #pragma unroll
    for (int nt = 0; nt < 5; ++nt) {
      #pragma unroll
      for (int ks = 0; ks < 3; ++ks) {
        f16x8 bf = *(const f16x8*)(wb + (nt * 16 + mr) * 96 + ks * 32 + q * 8);
        #pragma unroll
        for (int mt = 0; mt < 4; ++mt)
          acc[mt][nt] = __builtin_amdgcn_mfma_f32_16x16x32_f16(af[mt][ks], bf, acc[mt][nt], 0, 0, 0);
      }
    }
  }
  // epilogue: C layout col=lane&15, row=(lane>>4)*4+reg; scatter to targets
  #pragma unroll
  for (int mt = 0; mt < 4; ++mt) {
    #pragma unroll
    for (int reg = 0; reg < 4; ++reg) {
      int er = e0 + wave * 64 + mt * 16 + q * 4 + reg;
      int tg = Etgt[er];
      float* ap = agg + tg * 80;
      #pragma unroll
      for (int nt = 0; nt < 5; ++nt) {
        int i = nt * 16 + mr;
        if (i < 73) atomicAdd(ap + i, acc[mt][nt][reg]);
      }
    }
  }
}

// ---------------- agg fp32 -> f16 (padded) ----------------
__global__ void castagg_kernel(const float* __restrict__ agg, f16* __restrict__ aggf) {
  int t = blockIdx.x * 256 + threadIdx.x;  // exactly 786432
  int n = t / 96, k = t - n * 96;
  aggf[t] = (f16)((k < 73) ? agg[n * 80 + k] : 0.f);
}

// ---------------- GRU gates GEMMs: G[0]=agg@WihT, G[1]=h@WhhT ----------------
__global__ __launch_bounds__(256, 1) void grugemm_kernel(
    const f16* __restrict__ aggf, const f16* __restrict__ hf,
    const f16* __restrict__ WihT, const f16* __restrict__ WhhT,
    float* __restrict__ G) {
  __shared__ __align__(16) f16 As[128 * 96];
  __shared__ __align__(16) f16 Bs[224 * 96];
  const int tid = threadIdx.x;
  const int bz = blockIdx.x >> 6, bm = blockIdx.x & 63;
  const int m0 = bm * 128;
  const f16* A = bz ? hf : aggf;
  const f16* B = bz ? WhhT : WihT;
  float* out = G + bz * (NN * 224);
  stage_bytes(A + m0 * 96, As, 128 * 96 * 2, tid);
  stage_bytes(B, Bs, 224 * 96 * 2, tid);
  const int wave = tid >> 6, lane = tid & 63, q = lane >> 4, mr = lane & 15;
  __syncthreads();
  f16x8 af[2][3];
  #pragma unroll
  for (int mt = 0; mt < 2; ++mt)
    #pragma unroll
    for (int ks = 0; ks < 3; ++ks)
      af[mt][ks] = *(const f16x8*)(As + (wave * 32 + mt * 16 + mr) * 96 + ks * 32 + q * 8);
  f32x4 zero = {0.f, 0.f, 0.f, 0.f};
  f32x4 acc[2][14];
  #pragma unroll
  for (int mt = 0; mt < 2; ++mt)
    #pragma unroll
    for (int nt = 0; nt < 14; ++nt) acc[mt][nt] = zero;
  #pragma unroll
  for (int nt = 0; nt < 14; ++nt) {
    #pragma unroll
    for (int ks = 0; ks < 3; ++ks) {
      f16x8 bf = *(const f16x8*)(Bs + (nt * 16 + mr) * 96 + ks * 32 + q * 8);
      #pragma unroll
      for (int mt = 0; mt < 2; ++mt)
        acc[mt][nt] = __builtin_amdgcn_mfma_f32_16x16x32_f16(af[mt][ks], bf, acc[mt][nt], 0, 0, 0);
    }
  }
  #pragma unroll
  for (int mt = 0; mt < 2; ++mt)
    #pragma unroll
    for (int reg = 0; reg < 4; ++reg) {
      int row = m0 + wave * 32 + mt * 16 + q * 4 + reg;
      #pragma unroll
      for (int nt = 0; nt < 14; ++nt)
        out[row * 224 + nt * 16 + mr] = acc[mt][nt][reg];
    }
}

// ---------------- GRU elementwise update ----------------
__global__ void gate_kernel(const float* __restrict__ G, const float* __restrict__ bih,
                            const float* __restrict__ bhh, float* __restrict__ h,
                            f16* __restrict__ hf) {
  int idx = blockIdx.x * 256 + threadIdx.x;  // exactly 8192*73
  int n = idx / 73, i = idx - n * 73;
  const float* g0 = G + n * 224;
  const float* g1 = G + NN * 224 + n * 224;
  float rr = g0[i] + bih[i] + g1[i] + bhh[i];
  rr = 1.f / (1.f + expf(-rr));
  float zz = g0[73 + i] + bih[73 + i] + g1[73 + i] + bhh[73 + i];
  zz = 1.f / (1.f + expf(-zz));
  float nn_ = tanhf(g0[146 + i] + bih[146 + i] + rr * (g1[146 + i] + bhh[146 + i]));
  float hv = h[n * 96 + i];
  float hn = (1.f - zz) * nn_ + zz * hv;
  h[n * 96 + i] = hn;
  hf[n * 96 + i] = (f16)hn;
}

// ---------------- Set2Set helpers ----------------
__device__ __forceinline__ float wred_max(float v) {
  #pragma unroll
  for (int off = 32; off; off >>= 1) v = fmaxf(v, __shfl_xor(v, off, 64));
  return v;
}
__device__ __forceinline__ float wred_sum(float v) {
  #pragma unroll
  for (int off = 32; off; off >>= 1) v += __shfl_xor(v, off, 64);
  return v;
}
// fp32-accumulating f16 dot over 8 elements
__device__ __forceinline__ float dot8(f16x8 w, f16x8 x, float acc) {
#if HAS_FDOT2
  acc = __builtin_amdgcn_fdot2((f16x2)__builtin_shufflevector(w, w, 0, 1),
                               (f16x2)__builtin_shufflevector(x, x, 0, 1), acc, false);
  acc = __builtin_amdgcn_fdot2((f16x2)__builtin_shufflevector(w, w, 2, 3),
                               (f16x2)__builtin_shufflevector(x, x, 2, 3), acc, false);
  acc = __builtin_amdgcn_fdot2((f16x2)__builtin_shufflevector(w, w, 4, 5),
                               (f16x2)__builtin_shufflevector(x, x, 4, 5), acc, false);
  acc = __builtin_amdgcn_fdot2((f16x2)__builtin_shufflevector(w, w, 6, 7),
                               (f16x2)__builtin_shufflevector(x, x, 6, 7), acc, false);
#else
  #pragma unroll
  for (int e = 0; e < 8; ++e) acc += (float)w[e] * (float)x[e];
#endif
  return acc;
}

#define HCAP 200  // segment rows cached in LDS (58.4 KB); binomial max ~165, overflow reads global

// ---------------- Set2Set: one block per batch segment, 12 internal iterations ----------------
// h segment cached in LDS (stride 73 -> conflict-free for both access patterns);
// shuffle reductions (6 barriers/iter vs 24); LSTM gates via v_dot2_f32_f16.
__global__ __launch_bounds__(384, 1) void s2s_kernel(
    const float* __restrict__ h, const f16* __restrict__ Wli, const f16* __restrict__ Wlh,
    const float* __restrict__ lbih, const float* __restrict__ lbhh,
    const float* __restrict__ Wout, const float* __restrict__ bout,
    const int* __restrict__ batch, float* __restrict__ out) {
  __shared__ __align__(16) float hseg[HCAP * 73];   // 58400 B
  __shared__ __align__(16) f16 qstar_h[152];
  __shared__ __align__(16) f16 hh_h[80];
  __shared__ __align__(16) float hhv[80];
  __shared__ float ccv[73];
  __shared__ float gates[292];
  __shared__ float earr[384];
  __shared__ float red[16];
  __shared__ float rpart[5][73];
  __shared__ int sseg[2];
  const int t = threadIdx.x, b = blockIdx.x;
  const int wid = t >> 6, lane = t & 63;
  if (t < 2) {
    int key = b + t, lo = 0, hi = NN;
    while (lo < hi) { int mid = (lo + hi) >> 1; if (batch[mid] < key) lo = mid + 1; else hi = mid; }
    sseg[t] = lo;
  }
  if (t < 152) qstar_h[t] = (f16)0.f;
  if (t < 80) { hhv[t] = 0.f; hh_h[t] = (f16)0.f; }
  if (t < 73) ccv[t] = 0.f;
  f16x8 wih_r[19], whh_r[10];
  float bsum = 0.f;
  if (t < 292) {
    bsum = lbih[t] + lbhh[t];
    #pragma unroll
    for (int v = 0; v < 19; ++v) wih_r[v] = *(const f16x8*)(Wli + t * 152 + v * 8);
    #pragma unroll
    for (int v = 0; v < 10; ++v) whh_r[v] = *(const f16x8*)(Wlh + t * 80 + v * 8);
  }
  __syncthreads();  // sseg + inits visible
  const int s0 = sseg[0];
  int seg = sseg[1] - s0;
  if (seg > 384) seg = 384;
  const int c = seg < HCAP ? seg : HCAP;
  // stage segment h rows into LDS (one wave per row; unroll for load overlap)
  #pragma unroll 4
  for (int n = wid; n < c; n += 6) {
    const float* hr = h + (s0 + n) * 96;
    float* dr = hseg + n * 73;
    float v0 = hr[lane];
    float v1 = (lane < 9) ? hr[64 + lane] : 0.f;
    dr[lane] = v0;
    if (lane < 9) dr[64 + lane] = v1;
  }
  __syncthreads();

  for (int iter = 0; iter < 12; ++iter) {
    // LSTM gates: gate[t] = b + Wli[t,:]·qstar + Wlh[t,:]·hh
    if (t < 292) {
      float acc0 = bsum, acc1 = 0.f;
      #pragma unroll
      for (int v = 0; v < 19; ++v) {
        f16x8 x = *(const f16x8*)(qstar_h + v * 8);
        if (v & 1) acc1 = dot8(wih_r[v], x, acc1); else acc0 = dot8(wih_r[v], x, acc0);
      }
      #pragma unroll
      for (int v = 0; v < 10; ++v) {
        f16x8 x = *(const f16x8*)(hh_h + v * 8);
        if (v & 1) acc1 = dot8(whh_r[v], x, acc1); else acc0 = dot8(whh_r[v], x, acc0);
      }
      gates[t] = acc0 + acc1;
    }
    __syncthreads();
    if (t < 73) {
      float ig = 1.f / (1.f + expf(-gates[t]));
      float fg = 1.f / (1.f + expf(-gates[73 + t]));
      float gg = tanhf(gates[146 + t]);
      float og = 1.f / (1.f + expf(-gates[219 + t]));
      float cnew = fg * ccv[t] + ig * gg;
      ccv[t] = cnew;
      float hh = og * tanhf(cnew);
      hhv[t] = hh;
      hh_h[t] = (f16)hh;
      qstar_h[t] = (f16)hh;  // q part of next q_star
    }
    __syncthreads();
    // attention logits (node per thread, from LDS)
    float lmax = -3.4e38f;
    for (int n = t; n < seg; n += 384) {
      float e;
      if (n < HCAP) {
        const float* hr = hseg + n * 73;
        e = 0.f;
        #pragma unroll
        for (int i = 0; i < 73; ++i) e += hr[i] * hhv[i];
      } else {
        const float* hr = h + (s0 + n) * 96;
        e = hr[72] * hhv[72];
        #pragma unroll
        for (int i = 0; i < 72; i += 4) {
          float4 hv = *(const float4*)(hr + i);
          e += hv.x * hhv[i] + hv.y * hhv[i + 1] + hv.z * hhv[i + 2] + hv.w * hhv[i + 3];
        }
      }
      earr[n] = e;
      lmax = fmaxf(lmax, e);
    }
    float wm = wred_max(lmax);
    if (lane == 0) red[wid] = wm;
    __syncthreads();
    float mx = fmaxf(fmaxf(red[0], red[1]),
                     fmaxf(fmaxf(red[2], red[3]), fmaxf(red[4], red[5])));
    // exp + sum
    float lsum = 0.f;
    for (int n = t; n < seg; n += 384) {
      float a = expf(earr[n] - mx);
      earr[n] = a;
      lsum += a;
    }
    float wsum = wred_sum(lsum);
    if (lane == 0) red[8 + wid] = wsum;
    __syncthreads();  // earr(a) + partial sums visible
    float S = red[8] + red[9] + red[10] + red[11] + red[12] + red[13];
    // weighted readout r[i] = sum_n a_n * h[n][i] (5 chunks x 73)
    if (t < 365) {
      const int ch = t / 73, i = t - ch * 73;
      float r = 0.f;
      for (int ii = ch; ii < seg; ii += 5) {
        float hv = (ii < HCAP) ? hseg[ii * 73 + i] : h[(s0 + ii) * 96 + i];
        r += earr[ii] * hv;
      }
      rpart[ch][i] = r;
    }
    __syncthreads();
    if (t < 73) {
      float r = rpart[0][t] + rpart[1][t] + rpart[2][t] + rpart[3][t] + rpart[4][t];
      float invS = (S > 0.f) ? (1.f / S) : 0.f;
      qstar_h[73 + t] = (f16)(r * invS);
    }
    __syncthreads();
  }
  if (t == 0) {
    float a = bout[0];
    for (int i = 0; i < 73; ++i) a += hhv[i] * Wout[i];
    out[b] = a;
  }
}

// ---------------- workspace layout (bytes) ----------------
#define OFF_H      0u          // float [8192][96]
#define OFF_AGG    3145728u    // float [8192][80]
#define OFF_G      5767168u    // float [2][8192][224]
#define OFF_HF     20447232u   // f16 [8192][96]
#define OFF_AGGF   22020096u   // f16 [8192][96]
#define OFF_EHH    23592960u   // f16 [32768][80]
#define OFF_W2RT   28835840u   // f16 [74][80][96]
#define OFF_WIHT   29972480u   // f16 [224][96]
#define OFF_WHHT   30015488u   // f16 [224][96]
#define OFF_WLI    30058496u   // f16 [292][152]
#define OFF_WLH    30147264u   // f16 [292][80]

extern "C" void kernel_launch(void* const* d_in, const int* in_sizes, int n_in,
                              void* d_out, int out_size, void* d_ws, size_t ws_size,
                              hipStream_t stream) {
  const float* nf   = (const float*)d_in[0];
  const float* ef   = (const float*)d_in[1];
  const float* W_in = (const float*)d_in[2];
  const float* b_in = (const float*)d_in[3];
  const float* W1   = (const float*)d_in[4];
  const float* b1   = (const float*)d_in[5];
  const float* W2   = (const float*)d_in[6];
  const float* b2   = (const float*)d_in[7];
  const float* gWih = (const float*)d_in[8];
  const float* gWhh = (const float*)d_in[9];
  const float* gbih = (const float*)d_in[10];
  const float* gbhh = (const float*)d_in[11];
  const float* lWih = (const float*)d_in[12];
  const float* lWhh = (const float*)d_in[13];
  const float* lbih = (const float*)d_in[14];
  const float* lbhh = (const float*)d_in[15];
  const float* Wout = (const float*)d_in[16];
  const float* bout = (const float*)d_in[17];
  const int* Esrc   = (const int*)d_in[18];
  const int* Etgt   = (const int*)d_in[19];
  const int* batch  = (const int*)d_in[20];

  char* ws = (char*)d_ws;
  float* h    = (float*)(ws + OFF_H);
  float* agg  = (float*)(ws + OFF_AGG);
  float* G    = (float*)(ws + OFF_G);
  f16* hf     = (f16*)(ws + OFF_HF);
  f16* aggf   = (f16*)(ws + OFF_AGGF);
  f16* ehh    = (f16*)(ws + OFF_EHH);
  f16* W2rt   = (f16*)(ws + OFF_W2RT);
  f16* WihT   = (f16*)(ws + OFF_WIHT);
  f16* WhhT   = (f16*)(ws + OFF_WHHT);
  f16* Wli    = (f16*)(ws + OFF_WLI);
  f16* Wlh    = (f16*)(ws + OFF_WLH);

  prep_kernel<<<15965, 256, 0, stream>>>(nf, ef, W_in, b_in, W1, b1, W2, b2,
                                         gWih, gWhh, lWih, lWhh,
                                         h, hf, ehh, W2rt, WihT, WhhT, Wli, Wlh);
  for (int step = 0; step < 3; ++step) {
    hipMemsetAsync(agg, 0, NN * 80 * sizeof(float), stream);
    vgemm_kernel<<<256, 256, 0, stream>>>(ehh, h, W2rt, Esrc, Etgt, agg);
    castagg_kernel<<<3072, 256, 0, stream>>>(agg, aggf);
    grugemm_kernel<<<128, 256, 0, stream>>>(aggf, hf, WihT, WhhT, G);
    gate_kernel<<<2336, 256, 0, stream>>>(G, gbih, gbhh, h, hf);
  }
  s2s_kernel<<<64, 384, 0, stream>>>(h, Wli, Wlh, lbih, lbhh, Wout, bout, batch,
                                     (float*)d_out);
}